// Round 13
// baseline (944.761 us; speedup 1.0000x reference)
//
#include <hip/hip_runtime.h>

#define B_ 4
#define S_ 2048
#define D_ 1024
#define H_ 8
#define HD_ 128
#define FF_ 4096
#define R_ (B_*S_)          // 8192 rows

typedef __attribute__((ext_vector_type(8))) short short8;
typedef __attribute__((ext_vector_type(4))) float f32x4;

__device__ __forceinline__ unsigned short f2bf(float f) {
  unsigned int u = __float_as_uint(f);
  return (unsigned short)((u + 0x7fffu + ((u >> 16) & 1u)) >> 16);
}
__device__ __forceinline__ float bf2f(unsigned short s) {
  return __uint_as_float(((unsigned int)s) << 16);
}

typedef const __attribute__((address_space(1))) unsigned int* gas_p;
typedef __attribute__((address_space(3))) unsigned int* las_p;
__device__ __forceinline__ void gload16(const void* g, void* l) {
  __builtin_amdgcn_global_load_lds((gas_p)g, (las_p)l, 16, 0, 0);
}

// ---------- merged transpose+convert of ALL weights (1 dispatch) ----------
__global__ __launch_bounds__(256) void f2bf_t_all(
    const float* __restrict__ wq, const float* __restrict__ wk,
    const float* __restrict__ wv, const float* __restrict__ wo,
    const float* __restrict__ w1, const float* __restrict__ w3,
    const float* __restrict__ w2,
    unsigned short* __restrict__ qkvt, unsigned short* __restrict__ wot,
    unsigned short* __restrict__ w1t, unsigned short* __restrict__ w3t,
    unsigned short* __restrict__ w2t) {
  const int id = blockIdx.x;
  const int l = id >> 14, r = id & 16383;
  const float* src; unsigned short* dst; int Rows, Cols, t2;
  if (r < 4096) {
    Rows = 1024; Cols = 1024; t2 = r & 1023;
    const int wsel = r >> 10;
    if (wsel == 0)      { src = wq + (size_t)l*1048576u; dst = qkvt + (size_t)l*3145728u; }
    else if (wsel == 1) { src = wk + (size_t)l*1048576u; dst = qkvt + (size_t)l*3145728u + 1048576u; }
    else if (wsel == 2) { src = wv + (size_t)l*1048576u; dst = qkvt + (size_t)l*3145728u + 2097152u; }
    else                { src = wo + (size_t)l*1048576u; dst = wot + (size_t)l*1048576u; }
  } else if (r < 12288) {
    Rows = 1024; Cols = 4096; t2 = (r - 4096) & 4095;
    if (r < 8192) { src = w1 + (size_t)l*4194304u; dst = w1t + (size_t)l*4194304u; }
    else          { src = w3 + (size_t)l*4194304u; dst = w3t + (size_t)l*4194304u; }
  } else {
    Rows = 4096; Cols = 1024; t2 = r - 12288;
    src = w2 + (size_t)l*4194304u; dst = w2t + (size_t)l*4194304u;
  }
  const int lgc = (Cols == 4096) ? 7 : 5;
  const int bx = t2 & ((1 << lgc) - 1), by = t2 >> lgc;
  const int r0 = by * 32, c0 = bx * 32;
  __shared__ float tile[32][33];
  const int tx = threadIdx.x & 31, ty = threadIdx.x >> 5;
  #pragma unroll
  for (int j = 0; j < 32; j += 8)
    tile[ty + j][tx] = src[(size_t)(r0 + ty + j) * Cols + c0 + tx];
  __syncthreads();
  #pragma unroll
  for (int j = 0; j < 32; j += 8)
    dst[(size_t)(c0 + ty + j) * Rows + r0 + tx] = f2bf(tile[tx][ty + j]);
}

// ---------- RMSNorm f32 in -> bf16 out; optionally zero qk scale slots ----------
__global__ __launch_bounds__(256) void rmsnorm_f2b(const float* __restrict__ in,
    const float* __restrict__ w, unsigned short* __restrict__ out, float eps,
    float* __restrict__ qksc) {
  const int row = blockIdx.x, t = threadIdx.x;
  if (qksc && t == 0) { qksc[row] = 0.f; qksc[row + 8192] = 0.f; }
  const float4 xv = *(const float4*)&in[(size_t)row * D_ + t * 4];
  float p = xv.x*xv.x + xv.y*xv.y + xv.z*xv.z + xv.w*xv.w;
  #pragma unroll
  for (int off = 32; off >= 1; off >>= 1) p += __shfl_xor(p, off);
  __shared__ float red[4];
  if ((t & 63) == 0) red[t >> 6] = p;
  __syncthreads();
  float scl = rsqrtf((red[0] + red[1] + red[2] + red[3]) * (1.0f / D_) + eps);
  const float4 wv = *(const float4*)&w[t * 4];
  ((ushort4*)out)[(size_t)row * 256 + t] = make_ushort4(
      f2bf(xv.x*scl*wv.x), f2bf(xv.y*scl*wv.y), f2bf(xv.z*scl*wv.z), f2bf(xv.w*scl*wv.w));
}

// ---------- windowed ALiBi attention with inline qk-norm ----------
// qksc[0..8191] = sum q_row^2 (f32, from qkv epilogue), [8192..16383] = sum k_row^2
__global__ __launch_bounds__(256) void attn_k(const unsigned short* __restrict__ qkv,
    unsigned short* __restrict__ y, const float* __restrict__ qksc,
    const float* __restrict__ qw, const float* __restrict__ kw) {
  const int lane = threadIdx.x & 63;
  const int wid = (blockIdx.x * 256 + threadIdx.x) >> 6;
  const int i  = wid & (S_ - 1);
  const int bh = wid >> 11;
  const int hh = bh & (H_ - 1);
  const int b  = bh >> 3;
  const float slope = exp2f(-(float)(hh + 1));
  const float inv = 0.088388347648318447f;          // 1/sqrt(128)
  const int row_i = b * S_ + i;
  const size_t rowq = (size_t)row_i * 3072 + hh * HD_ + lane * 2;
  const ushort2 qv = *(const ushort2*)&qkv[rowq];
  const float2 qwv = *(const float2*)&qw[hh * HD_ + lane * 2];
  const float2 kwv = *(const float2*)&kw[hh * HD_ + lane * 2];
  const float sq = rsqrtf(qksc[row_i] * (1.0f / 1024.0f) + 1e-6f);
  const float qx = bf2f(qv.x) * qwv.x, qy = bf2f(qv.y) * qwv.y;
  float sc[17];
  #pragma unroll
  for (int jj = 0; jj < 17; ++jj) {
    int j = i - 16 + jj;
    int jc = j < 0 ? 0 : j;
    int row_j = b * S_ + jc;
    size_t koff = (size_t)row_j * 3072 + 1024 + hh * HD_ + lane * 2;
    ushort2 kv = *(const ushort2*)&qkv[koff];
    float p = qx * (bf2f(kv.x) * kwv.x) + qy * (bf2f(kv.y) * kwv.y);
    p += __shfl_xor(p, 32); p += __shfl_xor(p, 16); p += __shfl_xor(p, 8);
    p += __shfl_xor(p, 4);  p += __shfl_xor(p, 2);  p += __shfl_xor(p, 1);
    float sk = rsqrtf(qksc[8192 + row_j] * (1.0f / 1024.0f) + 1e-6f);
    sc[jj] = (j >= 0) ? (p * sq * sk * inv + slope * (float)(jj - 16)) : -1e30f;
  }
  float m = sc[0];
  #pragma unroll
  for (int jj = 1; jj < 17; ++jj) m = fmaxf(m, sc[jj]);
  float wsum = 0.f, ax = 0.f, ay = 0.f;
  #pragma unroll
  for (int jj = 0; jj < 17; ++jj) {
    int j = i - 16 + jj;
    int jc = j < 0 ? 0 : j;
    float wgt = expf(sc[jj] - m);
    size_t voff = ((size_t)(b * S_ + jc)) * 3072 + 2048 + hh * HD_ + lane * 2;
    ushort2 vv = *(const ushort2*)&qkv[voff];
    wsum += wgt; ax += wgt * bf2f(vv.x); ay += wgt * bf2f(vv.y);
  }
  float rs = 1.f / wsum;
  size_t yoff = ((size_t)(b * S_ + i)) * 1024 + hh * HD_ + lane * 2;
  *(ushort2*)&y[yoff] = make_ushort2(f2bf(ax * rs), f2bf(ay * rs));
}

// ======== 128x128 MFMA GEMM (proven 43%-class): C = A[M,K] @ Bt[N,K]^T ========
// 4 waves 64x64, BK=64, global_load_lds + both-sides XOR swizzle, 32KB LDS.
// NOTE: launch_bounds must stay (256,2) — declaring 3 waves/EU caps VGPR at 84,
// spilling the 128-VGPR accumulator set to scratch (r11: w13 142->299 µs).
__device__ __forceinline__ void stage_tile(const unsigned short* __restrict__ src,
    unsigned short* lds, int rowbase, int K, int k0, int t) {
  #pragma unroll
  for (int it = 0; it < 4; ++it) {
    int g = it * 256 + t;
    int row = g >> 3, slot = g & 7;
    int sc8 = (slot ^ (row & 7)) << 3;
    gload16(&src[(size_t)(rowbase + row) * K + k0 + sc8], &lds[g * 8]);
  }
}

// EPI 0: bf16 store; 1: h += sc[col]*acc; 2: h = x2 + sc[col]*acc;
// EPI 3: bf16 store + per-row sumsq atomics into (float*)sc (q: +0, k: +8192)
template<int EPI>
__global__ __launch_bounds__(256, 2) void gemm_tn(
    const unsigned short* __restrict__ A, const unsigned short* __restrict__ Bt,
    void* __restrict__ Cout, const float* __restrict__ sc,
    const float* __restrict__ x2, int M, int N, int K) {
  __shared__ __align__(16) unsigned short As[128 * 64];
  __shared__ __align__(16) unsigned short Bs[128 * 64];
  const int t = threadIdx.x;
  const int lane = t & 63, w = t >> 6;
  const int wr = w >> 1, wc = w & 1;
  const int br = blockIdx.y * 128, bc = blockIdx.x * 128;
  const int lr = lane & 15, lk = lane >> 4;
  const int xm = lr & 7;
  f32x4 acc[4][4];
  #pragma unroll
  for (int mi = 0; mi < 4; ++mi)
    #pragma unroll
    for (int ni = 0; ni < 4; ++ni) { f32x4 z = {0.f,0.f,0.f,0.f}; acc[mi][ni] = z; }
  for (int k0 = 0; k0 < K; k0 += 64) {
    stage_tile(A,  As, br, K, k0, t);
    stage_tile(Bt, Bs, bc, K, k0, t);
    __syncthreads();
    #pragma unroll
    for (int kk = 0; kk < 2; ++kk) {
      short8 af[4], bfr[4];
      #pragma unroll
      for (int mi = 0; mi < 4; ++mi)
        af[mi] = *(const short8*)&As[(wr*64 + mi*16 + lr) * 64 + (((kk*4 + lk) ^ xm) << 3)];
      #pragma unroll
      for (int ni = 0; ni < 4; ++ni)
        bfr[ni] = *(const short8*)&Bs[(wc*64 + ni*16 + lr) * 64 + (((kk*4 + lk) ^ xm) << 3)];
      #pragma unroll
      for (int mi = 0; mi < 4; ++mi)
        #pragma unroll
        for (int ni = 0; ni < 4; ++ni)
          acc[mi][ni] = __builtin_amdgcn_mfma_f32_16x16x32_bf16(af[mi], bfr[ni], acc[mi][ni], 0, 0, 0);
    }
    __syncthreads();
  }
  if (EPI == 0 || EPI == 3) {
    unsigned short* C = (unsigned short*)Cout;
    #pragma unroll
    for (int mi = 0; mi < 4; ++mi)
      #pragma unroll
      for (int ni = 0; ni < 4; ++ni) {
        int row = br + wr * 64 + mi * 16 + lk * 4;
        int col = bc + wc * 64 + ni * 16 + lr;
        #pragma unroll
        for (int r = 0; r < 4; ++r)
          C[(size_t)(row + r) * N + col] = f2bf(acc[mi][ni][r]);
      }
    if (EPI == 3 && bc < 2048) {
      float* sbuf = (float*)sc + (bc < 1024 ? 0 : 8192);
      #pragma unroll
      for (int mi = 0; mi < 4; ++mi)
        #pragma unroll
        for (int r = 0; r < 4; ++r) {
          float prt = 0.f;
          #pragma unroll
          for (int ni = 0; ni < 4; ++ni) { float v = acc[mi][ni][r]; prt += v * v; }
          prt += __shfl_xor(prt, 1); prt += __shfl_xor(prt, 2);
          prt += __shfl_xor(prt, 4); prt += __shfl_xor(prt, 8);
          if (lr == 0) atomicAdd(&sbuf[br + wr * 64 + mi * 16 + lk * 4 + r], prt);
        }
    }
  } else if (EPI == 1) {
    float* hp = (float*)Cout;
    #pragma unroll
    for (int ni = 0; ni < 4; ++ni) {
      int col = bc + wc * 64 + ni * 16 + lr;
      float sv = sc[col];
      #pragma unroll
      for (int mi = 0; mi < 4; ++mi) {
        int row = br + wr * 64 + mi * 16 + lk * 4;
        #pragma unroll
        for (int r = 0; r < 4; ++r)
          hp[(size_t)(row + r) * N + col] += sv * acc[mi][ni][r];
      }
    }
  } else {
    float* hp = (float*)Cout;
    #pragma unroll
    for (int ni = 0; ni < 4; ++ni) {
      int col = bc + wc * 64 + ni * 16 + lr;
      float sv = sc[col];
      #pragma unroll
      for (int mi = 0; mi < 4; ++mi) {
        int row = br + wr * 64 + mi * 16 + lk * 4;
        #pragma unroll
        for (int r = 0; r < 4; ++r)
          hp[(size_t)(row + r) * N + col] = x2[(size_t)(row + r) * N + col] + sv * acc[mi][ni][r];
      }
    }
  }
}

// ---------- fused FFN gate (128² dual-B, proven 142µs): G = bf16(silu(A@W1t^T)*(A@W3t^T)) ----------
__global__ __launch_bounds__(256, 2) void gemm_w13(
    const unsigned short* __restrict__ A, const unsigned short* __restrict__ B1t,
    const unsigned short* __restrict__ B3t, unsigned short* __restrict__ G,
    int M, int N, int K) {
  __shared__ __align__(16) unsigned short As[128 * 64];
  __shared__ __align__(16) unsigned short B1s[128 * 64];
  __shared__ __align__(16) unsigned short B3s[128 * 64];
  const int t = threadIdx.x;
  const int lane = t & 63, w = t >> 6;
  const int wr = w >> 1, wc = w & 1;
  const int br = blockIdx.y * 128, bc = blockIdx.x * 128;
  const int lr = lane & 15, lk = lane >> 4;
  const int xm = lr & 7;
  f32x4 acc1[4][4], acc3[4][4];
  #pragma unroll
  for (int mi = 0; mi < 4; ++mi)
    #pragma unroll
    for (int ni = 0; ni < 4; ++ni) {
      f32x4 z = {0.f,0.f,0.f,0.f}; acc1[mi][ni] = z; acc3[mi][ni] = z;
    }
  for (int k0 = 0; k0 < K; k0 += 64) {
    stage_tile(A,   As,  br, K, k0, t);
    stage_tile(B1t, B1s, bc, K, k0, t);
    stage_tile(B3t, B3s, bc, K, k0, t);
    __syncthreads();
    #pragma unroll
    for (int kk = 0; kk < 2; ++kk) {
      short8 af[4], b1r[4], b3r[4];
      #pragma unroll
      for (int mi = 0; mi < 4; ++mi)
        af[mi] = *(const short8*)&As[(wr*64 + mi*16 + lr) * 64 + (((kk*4 + lk) ^ xm) << 3)];
      #pragma unroll
      for (int ni = 0; ni < 4; ++ni) {
        b1r[ni] = *(const short8*)&B1s[(wc*64 + ni*16 + lr) * 64 + (((kk*4 + lk) ^ xm) << 3)];
        b3r[ni] = *(const short8*)&B3s[(wc*64 + ni*16 + lr) * 64 + (((kk*4 + lk) ^ xm) << 3)];
      }
      #pragma unroll
      for (int mi = 0; mi < 4; ++mi)
        #pragma unroll
        for (int ni = 0; ni < 4; ++ni) {
          acc1[mi][ni] = __builtin_amdgcn_mfma_f32_16x16x32_bf16(af[mi], b1r[ni], acc1[mi][ni], 0, 0, 0);
          acc3[mi][ni] = __builtin_amdgcn_mfma_f32_16x16x32_bf16(af[mi], b3r[ni], acc3[mi][ni], 0, 0, 0);
        }
    }
    __syncthreads();
  }
  #pragma unroll
  for (int mi = 0; mi < 4; ++mi)
    #pragma unroll
    for (int ni = 0; ni < 4; ++ni) {
      int row = br + wr * 64 + mi * 16 + lk * 4;
      int col = bc + wc * 64 + ni * 16 + lr;
      #pragma unroll
      for (int r = 0; r < 4; ++r) {
        float a1 = acc1[mi][ni][r], a3 = acc3[mi][ni][r];
        G[(size_t)(row + r) * N + col] = f2bf(a1 / (1.f + expf(-a1)) * a3);
      }
    }
}

extern "C" void kernel_launch(void* const* d_in, const int* in_sizes, int n_in,
                              void* d_out, int out_size, void* d_ws, size_t ws_size,
                              hipStream_t stream) {
  const float* x    = (const float*)d_in[0];
  const float* wq   = (const float*)d_in[1];
  const float* wk   = (const float*)d_in[2];
  const float* wv   = (const float*)d_in[3];
  const float* wo   = (const float*)d_in[4];
  const float* qnw  = (const float*)d_in[5];
  const float* knw  = (const float*)d_in[6];
  const float* w1   = (const float*)d_in[7];
  const float* w2   = (const float*)d_in[8];
  const float* w3   = (const float*)d_in[9];
  const float* anw  = (const float*)d_in[10];
  const float* fnw  = (const float*)d_in[11];
  const float* asc  = (const float*)d_in[12];
  const float* fsc  = (const float*)d_in[13];

  const size_t MB = 1024 * 1024;
  if (ws_size < 144 * MB) return;

  float* h = (float*)d_out;
  char* ws = (char*)d_ws;
  unsigned short* qkvt = (unsigned short*)ws;             // L x [3072][1024]
  unsigned short* wot  = qkvt + 2u * 3145728u;            // L x [1024][1024]
  unsigned short* w1t  = wot  + 2u * 1048576u;            // L x [4096][1024]
  unsigned short* w3t  = w1t  + 2u * 4194304u;
  unsigned short* w2t  = w3t  + 2u * 4194304u;            // L x [1024][4096]
  unsigned short* xn   = (unsigned short*)(ws + 64 * MB); // 16MB: xnorm / attn-y
  unsigned short* qkv  = (unsigned short*)(ws + 80 * MB); // 48MB [8192][3072]
  unsigned short* gate = qkv;                             // 64MB [8192][4096] (qkv dead)
  // qk sumsq scales: 64KB inside gate's tail. Dead during attention phase
  // (gate only written by w13 after attn consumed scales; re-zeroed next layer).
  float* qksc = (float*)(ws + 143 * MB);                  // [0..8191]=q, [8192..16383]=k

  f2bf_t_all<<<32768, 256, 0, stream>>>(wq, wk, wv, wo, w1, w3, w2,
                                        qkvt, wot, w1t, w3t, w2t);

  for (int l = 0; l < 2; ++l) {
    // ---- attention ----
    rmsnorm_f2b<<<R_, 256, 0, stream>>>(l == 0 ? x : h, anw + l * D_, xn, 0.01f, qksc);
    gemm_tn<3><<<dim3(24, 64), 256, 0, stream>>>(xn, qkvt + (size_t)l*3145728u, qkv,
                                                 qksc, nullptr, R_, 3072, 1024);
    attn_k<<<R_ * H_ / 4, 256, 0, stream>>>(qkv, xn, qksc,
                                            qnw + l * 1024, knw + l * 1024);
    if (l == 0)
      gemm_tn<2><<<dim3(8, 64), 256, 0, stream>>>(xn, wot, h, asc, x, R_, 1024, 1024);
    else
      gemm_tn<1><<<dim3(8, 64), 256, 0, stream>>>(xn, wot + 1048576u, h, asc + D_,
                                                  nullptr, R_, 1024, 1024);
    // ---- FFN ----
    rmsnorm_f2b<<<R_, 256, 0, stream>>>(h, fnw + l * D_, xn, 0.01f, nullptr);
    gemm_w13<<<dim3(32, 64), 256, 0, stream>>>(xn, w1t + (size_t)l*4194304u,
                                               w3t + (size_t)l*4194304u, gate, R_, 4096, 1024);
    gemm_tn<1><<<dim3(8, 64), 256, 0, stream>>>(gate, w2t + (size_t)l*4194304u, h,
                                                fsc + l * D_, nullptr, R_, 1024, 4096);
  }
}

// Round 14
// 897.249 us; speedup vs baseline: 1.0530x; 1.0530x over previous
//
#include <hip/hip_runtime.h>

#define B_ 4
#define S_ 2048
#define D_ 1024
#define H_ 8
#define HD_ 128
#define FF_ 4096
#define R_ (B_*S_)          // 8192 rows

typedef __attribute__((ext_vector_type(8))) short short8;
typedef __attribute__((ext_vector_type(4))) float f32x4;

__device__ __forceinline__ unsigned short f2bf(float f) {
  unsigned int u = __float_as_uint(f);
  return (unsigned short)((u + 0x7fffu + ((u >> 16) & 1u)) >> 16);
}
__device__ __forceinline__ float bf2f(unsigned short s) {
  return __uint_as_float(((unsigned int)s) << 16);
}

typedef const __attribute__((address_space(1))) unsigned int* gas_p;
typedef __attribute__((address_space(3))) unsigned int* las_p;
__device__ __forceinline__ void gload16(const void* g, void* l) {
  __builtin_amdgcn_global_load_lds((gas_p)g, (las_p)l, 16, 0, 0);
}

// ---------- merged transpose+convert of ALL weights (1 dispatch) ----------
__global__ __launch_bounds__(256) void f2bf_t_all(
    const float* __restrict__ wq, const float* __restrict__ wk,
    const float* __restrict__ wv, const float* __restrict__ wo,
    const float* __restrict__ w1, const float* __restrict__ w3,
    const float* __restrict__ w2,
    unsigned short* __restrict__ qkvt, unsigned short* __restrict__ wot,
    unsigned short* __restrict__ w1t, unsigned short* __restrict__ w3t,
    unsigned short* __restrict__ w2t) {
  const int id = blockIdx.x;
  const int l = id >> 14, r = id & 16383;
  const float* src; unsigned short* dst; int Rows, Cols, t2;
  if (r < 4096) {
    Rows = 1024; Cols = 1024; t2 = r & 1023;
    const int wsel = r >> 10;
    if (wsel == 0)      { src = wq + (size_t)l*1048576u; dst = qkvt + (size_t)l*3145728u; }
    else if (wsel == 1) { src = wk + (size_t)l*1048576u; dst = qkvt + (size_t)l*3145728u + 1048576u; }
    else if (wsel == 2) { src = wv + (size_t)l*1048576u; dst = qkvt + (size_t)l*3145728u + 2097152u; }
    else                { src = wo + (size_t)l*1048576u; dst = wot + (size_t)l*1048576u; }
  } else if (r < 12288) {
    Rows = 1024; Cols = 4096; t2 = (r - 4096) & 4095;
    if (r < 8192) { src = w1 + (size_t)l*4194304u; dst = w1t + (size_t)l*4194304u; }
    else          { src = w3 + (size_t)l*4194304u; dst = w3t + (size_t)l*4194304u; }
  } else {
    Rows = 4096; Cols = 1024; t2 = r - 12288;
    src = w2 + (size_t)l*4194304u; dst = w2t + (size_t)l*4194304u;
  }
  const int lgc = (Cols == 4096) ? 7 : 5;
  const int bx = t2 & ((1 << lgc) - 1), by = t2 >> lgc;
  const int r0 = by * 32, c0 = bx * 32;
  __shared__ float tile[32][33];
  const int tx = threadIdx.x & 31, ty = threadIdx.x >> 5;
  #pragma unroll
  for (int j = 0; j < 32; j += 8)
    tile[ty + j][tx] = src[(size_t)(r0 + ty + j) * Cols + c0 + tx];
  __syncthreads();
  #pragma unroll
  for (int j = 0; j < 32; j += 8)
    dst[(size_t)(c0 + ty + j) * Rows + r0 + tx] = f2bf(tile[tx][ty + j]);
}

// ---------- RMSNorm f32 in -> bf16 out ----------
__global__ __launch_bounds__(256) void rmsnorm_f2b(const float* __restrict__ in,
    const float* __restrict__ w, unsigned short* __restrict__ out, float eps) {
  const int row = blockIdx.x, t = threadIdx.x;
  const float4 xv = *(const float4*)&in[(size_t)row * D_ + t * 4];
  float p = xv.x*xv.x + xv.y*xv.y + xv.z*xv.z + xv.w*xv.w;
  #pragma unroll
  for (int off = 32; off >= 1; off >>= 1) p += __shfl_xor(p, off);
  __shared__ float red[4];
  if ((t & 63) == 0) red[t >> 6] = p;
  __syncthreads();
  float scl = rsqrtf((red[0] + red[1] + red[2] + red[3]) * (1.0f / D_) + eps);
  const float4 wv = *(const float4*)&w[t * 4];
  ((ushort4*)out)[(size_t)row * 256 + t] = make_ushort4(
      f2bf(xv.x*scl*wv.x), f2bf(xv.y*scl*wv.y), f2bf(xv.z*scl*wv.z), f2bf(xv.w*scl*wv.w));
}

// ---------- fused q/k RMSNorm over the 1024-wide flat projection, in-place ----------
// NOTE (r13 lesson): do NOT fold this into attn_k — the per-channel weight then
// gets applied 17x per key inside the window loop (+57 µs net).
__global__ __launch_bounds__(256) void qknorm_k(unsigned short* __restrict__ qkv,
    const float* __restrict__ qw, const float* __restrict__ kw) {
  const int row = blockIdx.x, t = threadIdx.x;
  unsigned short* qp = qkv + (size_t)row * 3072;
  unsigned short* kp = qp + 1024;
  const ushort4 qv = ((const ushort4*)qp)[t];
  const ushort4 kv = ((const ushort4*)kp)[t];
  float q0 = bf2f(qv.x), q1 = bf2f(qv.y), q2 = bf2f(qv.z), q3 = bf2f(qv.w);
  float k0 = bf2f(kv.x), k1 = bf2f(kv.y), k2 = bf2f(kv.z), k3 = bf2f(kv.w);
  float pq = q0*q0 + q1*q1 + q2*q2 + q3*q3;
  float pk = k0*k0 + k1*k1 + k2*k2 + k3*k3;
  #pragma unroll
  for (int off = 32; off >= 1; off >>= 1) { pq += __shfl_xor(pq, off); pk += __shfl_xor(pk, off); }
  __shared__ float redq[4], redk[4];
  if ((t & 63) == 0) { redq[t >> 6] = pq; redk[t >> 6] = pk; }
  __syncthreads();
  float sq = rsqrtf((redq[0]+redq[1]+redq[2]+redq[3]) * (1.0f / D_) + 1e-6f);
  float sk = rsqrtf((redk[0]+redk[1]+redk[2]+redk[3]) * (1.0f / D_) + 1e-6f);
  const float4 qwv = *(const float4*)&qw[t * 4];
  const float4 kwv = *(const float4*)&kw[t * 4];
  ((ushort4*)qp)[t] = make_ushort4(f2bf(q0*sq*qwv.x), f2bf(q1*sq*qwv.y),
                                   f2bf(q2*sq*qwv.z), f2bf(q3*sq*qwv.w));
  ((ushort4*)kp)[t] = make_ushort4(f2bf(k0*sk*kwv.x), f2bf(k1*sk*kwv.y),
                                   f2bf(k2*sk*kwv.z), f2bf(k3*sk*kwv.w));
}

// ---------- windowed ALiBi attention: 1 wave per (b,h,i); q/k/v packed [8192][3072] ----------
__global__ __launch_bounds__(256) void attn_k(const unsigned short* __restrict__ qkv,
    unsigned short* __restrict__ y) {
  const int lane = threadIdx.x & 63;
  const int wid = (blockIdx.x * 256 + threadIdx.x) >> 6;
  const int i  = wid & (S_ - 1);
  const int bh = wid >> 11;
  const int hh = bh & (H_ - 1);
  const int b  = bh >> 3;
  const float slope = exp2f(-(float)(hh + 1));
  const float inv = 0.088388347648318447f;          // 1/sqrt(128)
  const size_t rowq = ((size_t)(b * S_ + i)) * 3072 + hh * HD_ + lane * 2;
  const ushort2 qv = *(const ushort2*)&qkv[rowq];
  const float qx = bf2f(qv.x), qy = bf2f(qv.y);
  float sc[17];
  #pragma unroll
  for (int jj = 0; jj < 17; ++jj) {
    int j = i - 16 + jj;
    int jc = j < 0 ? 0 : j;
    size_t koff = ((size_t)(b * S_ + jc)) * 3072 + 1024 + hh * HD_ + lane * 2;
    ushort2 kv = *(const ushort2*)&qkv[koff];
    float p = qx * bf2f(kv.x) + qy * bf2f(kv.y);
    p += __shfl_xor(p, 32); p += __shfl_xor(p, 16); p += __shfl_xor(p, 8);
    p += __shfl_xor(p, 4);  p += __shfl_xor(p, 2);  p += __shfl_xor(p, 1);
    sc[jj] = (j >= 0) ? (p * inv + slope * (float)(jj - 16)) : -1e30f;
  }
  float m = sc[0];
  #pragma unroll
  for (int jj = 1; jj < 17; ++jj) m = fmaxf(m, sc[jj]);
  float wsum = 0.f, ax = 0.f, ay = 0.f;
  #pragma unroll
  for (int jj = 0; jj < 17; ++jj) {
    int j = i - 16 + jj;
    int jc = j < 0 ? 0 : j;
    float wgt = expf(sc[jj] - m);
    size_t voff = ((size_t)(b * S_ + jc)) * 3072 + 2048 + hh * HD_ + lane * 2;
    ushort2 vv = *(const ushort2*)&qkv[voff];
    wsum += wgt; ax += wgt * bf2f(vv.x); ay += wgt * bf2f(vv.y);
  }
  float rs = 1.f / wsum;
  size_t yoff = ((size_t)(b * S_ + i)) * 1024 + hh * HD_ + lane * 2;
  *(ushort2*)&y[yoff] = make_ushort2(f2bf(ax * rs), f2bf(ay * rs));
}

// ======== 128x128 MFMA GEMM (proven 43%-class): C = A[M,K] @ Bt[N,K]^T ========
// 4 waves 64x64, BK=64, global_load_lds + both-sides XOR swizzle, 32KB LDS.
// NOTE: launch_bounds must stay (256,2) — declaring 3 waves/EU caps VGPR at 84,
// spilling the 128-VGPR accumulator set to scratch (r11: w13 142->299 µs).
__device__ __forceinline__ void stage_tile(const unsigned short* __restrict__ src,
    unsigned short* lds, int rowbase, int K, int k0, int t) {
  #pragma unroll
  for (int it = 0; it < 4; ++it) {
    int g = it * 256 + t;
    int row = g >> 3, slot = g & 7;
    int sc8 = (slot ^ (row & 7)) << 3;
    gload16(&src[(size_t)(rowbase + row) * K + k0 + sc8], &lds[g * 8]);
  }
}

// EPI 0: bf16 store; 1: h += sc[col]*acc; 2: h = x2 + sc[col]*acc
template<int EPI>
__global__ __launch_bounds__(256, 2) void gemm_tn(
    const unsigned short* __restrict__ A, const unsigned short* __restrict__ Bt,
    void* __restrict__ Cout, const float* __restrict__ sc,
    const float* __restrict__ x2, int M, int N, int K) {
  __shared__ __align__(16) unsigned short As[128 * 64];
  __shared__ __align__(16) unsigned short Bs[128 * 64];
  const int t = threadIdx.x;
  const int lane = t & 63, w = t >> 6;
  const int wr = w >> 1, wc = w & 1;
  const int br = blockIdx.y * 128, bc = blockIdx.x * 128;
  const int lr = lane & 15, lk = lane >> 4;
  const int xm = lr & 7;
  f32x4 acc[4][4];
  #pragma unroll
  for (int mi = 0; mi < 4; ++mi)
    #pragma unroll
    for (int ni = 0; ni < 4; ++ni) { f32x4 z = {0.f,0.f,0.f,0.f}; acc[mi][ni] = z; }
  for (int k0 = 0; k0 < K; k0 += 64) {
    stage_tile(A,  As, br, K, k0, t);
    stage_tile(Bt, Bs, bc, K, k0, t);
    __syncthreads();
    #pragma unroll
    for (int kk = 0; kk < 2; ++kk) {
      short8 af[4], bfr[4];
      #pragma unroll
      for (int mi = 0; mi < 4; ++mi)
        af[mi] = *(const short8*)&As[(wr*64 + mi*16 + lr) * 64 + (((kk*4 + lk) ^ xm) << 3)];
      #pragma unroll
      for (int ni = 0; ni < 4; ++ni)
        bfr[ni] = *(const short8*)&Bs[(wc*64 + ni*16 + lr) * 64 + (((kk*4 + lk) ^ xm) << 3)];
      #pragma unroll
      for (int mi = 0; mi < 4; ++mi)
        #pragma unroll
        for (int ni = 0; ni < 4; ++ni)
          acc[mi][ni] = __builtin_amdgcn_mfma_f32_16x16x32_bf16(af[mi], bfr[ni], acc[mi][ni], 0, 0, 0);
    }
    __syncthreads();
  }
  if (EPI == 0) {
    unsigned short* C = (unsigned short*)Cout;
    #pragma unroll
    for (int mi = 0; mi < 4; ++mi)
      #pragma unroll
      for (int ni = 0; ni < 4; ++ni) {
        int row = br + wr * 64 + mi * 16 + lk * 4;
        int col = bc + wc * 64 + ni * 16 + lr;
        #pragma unroll
        for (int r = 0; r < 4; ++r)
          C[(size_t)(row + r) * N + col] = f2bf(acc[mi][ni][r]);
      }
  } else if (EPI == 1) {
    float* hp = (float*)Cout;
    #pragma unroll
    for (int ni = 0; ni < 4; ++ni) {
      int col = bc + wc * 64 + ni * 16 + lr;
      float sv = sc[col];
      #pragma unroll
      for (int mi = 0; mi < 4; ++mi) {
        int row = br + wr * 64 + mi * 16 + lk * 4;
        #pragma unroll
        for (int r = 0; r < 4; ++r)
          hp[(size_t)(row + r) * N + col] += sv * acc[mi][ni][r];
      }
    }
  } else {
    float* hp = (float*)Cout;
    #pragma unroll
    for (int ni = 0; ni < 4; ++ni) {
      int col = bc + wc * 64 + ni * 16 + lr;
      float sv = sc[col];
      #pragma unroll
      for (int mi = 0; mi < 4; ++mi) {
        int row = br + wr * 64 + mi * 16 + lk * 4;
        #pragma unroll
        for (int r = 0; r < 4; ++r)
          hp[(size_t)(row + r) * N + col] = x2[(size_t)(row + r) * N + col] + sv * acc[mi][ni][r];
      }
    }
  }
}

// ---------- fused FFN gate (128² dual-B, proven 142µs): G = bf16(silu(A@W1t^T)*(A@W3t^T)) ----------
__global__ __launch_bounds__(256, 2) void gemm_w13(
    const unsigned short* __restrict__ A, const unsigned short* __restrict__ B1t,
    const unsigned short* __restrict__ B3t, unsigned short* __restrict__ G,
    int M, int N, int K) {
  __shared__ __align__(16) unsigned short As[128 * 64];
  __shared__ __align__(16) unsigned short B1s[128 * 64];
  __shared__ __align__(16) unsigned short B3s[128 * 64];
  const int t = threadIdx.x;
  const int lane = t & 63, w = t >> 6;
  const int wr = w >> 1, wc = w & 1;
  const int br = blockIdx.y * 128, bc = blockIdx.x * 128;
  const int lr = lane & 15, lk = lane >> 4;
  const int xm = lr & 7;
  f32x4 acc1[4][4], acc3[4][4];
  #pragma unroll
  for (int mi = 0; mi < 4; ++mi)
    #pragma unroll
    for (int ni = 0; ni < 4; ++ni) {
      f32x4 z = {0.f,0.f,0.f,0.f}; acc1[mi][ni] = z; acc3[mi][ni] = z;
    }
  for (int k0 = 0; k0 < K; k0 += 64) {
    stage_tile(A,   As,  br, K, k0, t);
    stage_tile(B1t, B1s, bc, K, k0, t);
    stage_tile(B3t, B3s, bc, K, k0, t);
    __syncthreads();
    #pragma unroll
    for (int kk = 0; kk < 2; ++kk) {
      short8 af[4], b1r[4], b3r[4];
      #pragma unroll
      for (int mi = 0; mi < 4; ++mi)
        af[mi] = *(const short8*)&As[(wr*64 + mi*16 + lr) * 64 + (((kk*4 + lk) ^ xm) << 3)];
      #pragma unroll
      for (int ni = 0; ni < 4; ++ni) {
        b1r[ni] = *(const short8*)&B1s[(wc*64 + ni*16 + lr) * 64 + (((kk*4 + lk) ^ xm) << 3)];
        b3r[ni] = *(const short8*)&B3s[(wc*64 + ni*16 + lr) * 64 + (((kk*4 + lk) ^ xm) << 3)];
      }
      #pragma unroll
      for (int mi = 0; mi < 4; ++mi)
        #pragma unroll
        for (int ni = 0; ni < 4; ++ni) {
          acc1[mi][ni] = __builtin_amdgcn_mfma_f32_16x16x32_bf16(af[mi], b1r[ni], acc1[mi][ni], 0, 0, 0);
          acc3[mi][ni] = __builtin_amdgcn_mfma_f32_16x16x32_bf16(af[mi], b3r[ni], acc3[mi][ni], 0, 0, 0);
        }
    }
    __syncthreads();
  }
  #pragma unroll
  for (int mi = 0; mi < 4; ++mi)
    #pragma unroll
    for (int ni = 0; ni < 4; ++ni) {
      int row = br + wr * 64 + mi * 16 + lk * 4;
      int col = bc + wc * 64 + ni * 16 + lr;
      #pragma unroll
      for (int r = 0; r < 4; ++r) {
        float a1 = acc1[mi][ni][r], a3 = acc3[mi][ni][r];
        G[(size_t)(row + r) * N + col] = f2bf(a1 / (1.f + expf(-a1)) * a3);
      }
    }
}

extern "C" void kernel_launch(void* const* d_in, const int* in_sizes, int n_in,
                              void* d_out, int out_size, void* d_ws, size_t ws_size,
                              hipStream_t stream) {
  const float* x    = (const float*)d_in[0];
  const float* wq   = (const float*)d_in[1];
  const float* wk   = (const float*)d_in[2];
  const float* wv   = (const float*)d_in[3];
  const float* wo   = (const float*)d_in[4];
  const float* qnw  = (const float*)d_in[5];
  const float* knw  = (const float*)d_in[6];
  const float* w1   = (const float*)d_in[7];
  const float* w2   = (const float*)d_in[8];
  const float* w3   = (const float*)d_in[9];
  const float* anw  = (const float*)d_in[10];
  const float* fnw  = (const float*)d_in[11];
  const float* asc  = (const float*)d_in[12];
  const float* fsc  = (const float*)d_in[13];

  const size_t MB = 1024 * 1024;
  if (ws_size < 144 * MB) return;

  float* h = (float*)d_out;
  char* ws = (char*)d_ws;
  unsigned short* qkvt = (unsigned short*)ws;             // L x [3072][1024]
  unsigned short* wot  = qkvt + 2u * 3145728u;            // L x [1024][1024]
  unsigned short* w1t  = wot  + 2u * 1048576u;            // L x [4096][1024]
  unsigned short* w3t  = w1t  + 2u * 4194304u;
  unsigned short* w2t  = w3t  + 2u * 4194304u;            // L x [1024][4096]
  unsigned short* xn   = (unsigned short*)(ws + 64 * MB); // 16MB: xnorm / attn-y
  unsigned short* qkv  = (unsigned short*)(ws + 80 * MB); // 48MB [8192][3072]
  unsigned short* gate = qkv;                             // 64MB [8192][4096] (qkv dead)

  f2bf_t_all<<<32768, 256, 0, stream>>>(wq, wk, wv, wo, w1, w3, w2,
                                        qkvt, wot, w1t, w3t, w2t);

  for (int l = 0; l < 2; ++l) {
    // ---- attention ----
    rmsnorm_f2b<<<R_, 256, 0, stream>>>(l == 0 ? x : h, anw + l * D_, xn, 0.01f);
    gemm_tn<0><<<dim3(24, 64), 256, 0, stream>>>(xn, qkvt + (size_t)l*3145728u, qkv,
                                                 nullptr, nullptr, R_, 3072, 1024);
    qknorm_k<<<R_, 256, 0, stream>>>(qkv, qnw + l * 1024, knw + l * 1024);
    attn_k<<<R_ * H_ / 4, 256, 0, stream>>>(qkv, xn);
    if (l == 0)
      gemm_tn<2><<<dim3(8, 64), 256, 0, stream>>>(xn, wot, h, asc, x, R_, 1024, 1024);
    else
      gemm_tn<1><<<dim3(8, 64), 256, 0, stream>>>(xn, wot + 1048576u, h, asc + D_,
                                                  nullptr, R_, 1024, 1024);
    // ---- FFN ----
    rmsnorm_f2b<<<R_, 256, 0, stream>>>(h, fnw + l * D_, xn, 0.01f);
    gemm_w13<<<dim3(32, 64), 256, 0, stream>>>(xn, w1t + (size_t)l*4194304u,
                                               w3t + (size_t)l*4194304u, gate, R_, 4096, 1024);
    gemm_tn<1><<<dim3(8, 64), 256, 0, stream>>>(gate, w2t + (size_t)l*4194304u, h,
                                                fsc + l * D_, nullptr, R_, 1024, 4096);
  }
}

// Round 15
// 853.459 us; speedup vs baseline: 1.1070x; 1.0513x over previous
//
#include <hip/hip_runtime.h>

#define B_ 4
#define S_ 2048
#define D_ 1024
#define H_ 8
#define HD_ 128
#define FF_ 4096
#define R_ (B_*S_)          // 8192 rows

typedef __attribute__((ext_vector_type(8))) short short8;
typedef __attribute__((ext_vector_type(4))) float f32x4;

__device__ __forceinline__ unsigned short f2bf(float f) {
  unsigned int u = __float_as_uint(f);
  return (unsigned short)((u + 0x7fffu + ((u >> 16) & 1u)) >> 16);
}
__device__ __forceinline__ float bf2f(unsigned short s) {
  return __uint_as_float(((unsigned int)s) << 16);
}

typedef const __attribute__((address_space(1))) unsigned int* gas_p;
typedef __attribute__((address_space(3))) unsigned int* las_p;
__device__ __forceinline__ void gload16(const void* g, void* l) {
  __builtin_amdgcn_global_load_lds((gas_p)g, (las_p)l, 16, 0, 0);
}

// ---------- merged transpose+convert of ALL weights (1 dispatch) ----------
__global__ __launch_bounds__(256) void f2bf_t_all(
    const float* __restrict__ wq, const float* __restrict__ wk,
    const float* __restrict__ wv, const float* __restrict__ wo,
    const float* __restrict__ w1, const float* __restrict__ w3,
    const float* __restrict__ w2,
    unsigned short* __restrict__ qkvt, unsigned short* __restrict__ wot,
    unsigned short* __restrict__ w1t, unsigned short* __restrict__ w3t,
    unsigned short* __restrict__ w2t) {
  const int id = blockIdx.x;
  const int l = id >> 14, r = id & 16383;
  const float* src; unsigned short* dst; int Rows, Cols, t2;
  if (r < 4096) {
    Rows = 1024; Cols = 1024; t2 = r & 1023;
    const int wsel = r >> 10;
    if (wsel == 0)      { src = wq + (size_t)l*1048576u; dst = qkvt + (size_t)l*3145728u; }
    else if (wsel == 1) { src = wk + (size_t)l*1048576u; dst = qkvt + (size_t)l*3145728u + 1048576u; }
    else if (wsel == 2) { src = wv + (size_t)l*1048576u; dst = qkvt + (size_t)l*3145728u + 2097152u; }
    else                { src = wo + (size_t)l*1048576u; dst = wot + (size_t)l*1048576u; }
  } else if (r < 12288) {
    Rows = 1024; Cols = 4096; t2 = (r - 4096) & 4095;
    if (r < 8192) { src = w1 + (size_t)l*4194304u; dst = w1t + (size_t)l*4194304u; }
    else          { src = w3 + (size_t)l*4194304u; dst = w3t + (size_t)l*4194304u; }
  } else {
    Rows = 4096; Cols = 1024; t2 = r - 12288;
    src = w2 + (size_t)l*4194304u; dst = w2t + (size_t)l*4194304u;
  }
  const int lgc = (Cols == 4096) ? 7 : 5;
  const int bx = t2 & ((1 << lgc) - 1), by = t2 >> lgc;
  const int r0 = by * 32, c0 = bx * 32;
  __shared__ float tile[32][33];
  const int tx = threadIdx.x & 31, ty = threadIdx.x >> 5;
  #pragma unroll
  for (int j = 0; j < 32; j += 8)
    tile[ty + j][tx] = src[(size_t)(r0 + ty + j) * Cols + c0 + tx];
  __syncthreads();
  #pragma unroll
  for (int j = 0; j < 32; j += 8)
    dst[(size_t)(c0 + ty + j) * Rows + r0 + tx] = f2bf(tile[tx][ty + j]);
}

// ---------- RMSNorm f32 in -> bf16 out ----------
__global__ __launch_bounds__(256) void rmsnorm_f2b(const float* __restrict__ in,
    const float* __restrict__ w, unsigned short* __restrict__ out, float eps) {
  const int row = blockIdx.x, t = threadIdx.x;
  const float4 xv = *(const float4*)&in[(size_t)row * D_ + t * 4];
  float p = xv.x*xv.x + xv.y*xv.y + xv.z*xv.z + xv.w*xv.w;
  #pragma unroll
  for (int off = 32; off >= 1; off >>= 1) p += __shfl_xor(p, off);
  __shared__ float red[4];
  if ((t & 63) == 0) red[t >> 6] = p;
  __syncthreads();
  float scl = rsqrtf((red[0] + red[1] + red[2] + red[3]) * (1.0f / D_) + eps);
  const float4 wv = *(const float4*)&w[t * 4];
  ((ushort4*)out)[(size_t)row * 256 + t] = make_ushort4(
      f2bf(xv.x*scl*wv.x), f2bf(xv.y*scl*wv.y), f2bf(xv.z*scl*wv.z), f2bf(xv.w*scl*wv.w));
}

// ---------- fused q/k RMSNorm over the 1024-wide flat projection, in-place ----------
// NOTE (r13 lesson): do NOT fold this into attn_k — the per-channel weight then
// gets applied 17x per key inside the window loop (+57 µs net).
__global__ __launch_bounds__(256) void qknorm_k(unsigned short* __restrict__ qkv,
    const float* __restrict__ qw, const float* __restrict__ kw) {
  const int row = blockIdx.x, t = threadIdx.x;
  unsigned short* qp = qkv + (size_t)row * 3072;
  unsigned short* kp = qp + 1024;
  const ushort4 qv = ((const ushort4*)qp)[t];
  const ushort4 kv = ((const ushort4*)kp)[t];
  float q0 = bf2f(qv.x), q1 = bf2f(qv.y), q2 = bf2f(qv.z), q3 = bf2f(qv.w);
  float k0 = bf2f(kv.x), k1 = bf2f(kv.y), k2 = bf2f(kv.z), k3 = bf2f(kv.w);
  float pq = q0*q0 + q1*q1 + q2*q2 + q3*q3;
  float pk = k0*k0 + k1*k1 + k2*k2 + k3*k3;
  #pragma unroll
  for (int off = 32; off >= 1; off >>= 1) { pq += __shfl_xor(pq, off); pk += __shfl_xor(pk, off); }
  __shared__ float redq[4], redk[4];
  if ((t & 63) == 0) { redq[t >> 6] = pq; redk[t >> 6] = pk; }
  __syncthreads();
  float sq = rsqrtf((redq[0]+redq[1]+redq[2]+redq[3]) * (1.0f / D_) + 1e-6f);
  float sk = rsqrtf((redk[0]+redk[1]+redk[2]+redk[3]) * (1.0f / D_) + 1e-6f);
  const float4 qwv = *(const float4*)&qw[t * 4];
  const float4 kwv = *(const float4*)&kw[t * 4];
  ((ushort4*)qp)[t] = make_ushort4(f2bf(q0*sq*qwv.x), f2bf(q1*sq*qwv.y),
                                   f2bf(q2*sq*qwv.z), f2bf(q3*sq*qwv.w));
  ((ushort4*)kp)[t] = make_ushort4(f2bf(k0*sk*kwv.x), f2bf(k1*sk*kwv.y),
                                   f2bf(k2*sk*kwv.z), f2bf(k3*sk*kwv.w));
}

// ---------- windowed ALiBi attention: 16 lanes per query (4 queries/wave) ----------
// Each lane covers 8 channels via short8 (16B loads, G13 sweet spot); dot
// reduce = 4 shfl_xor stages confined to the 16-lane quarter. Consecutive
// queries in a wave share 14/17 of the K/V window (L1/L2 hits).
__global__ __launch_bounds__(256) void attn_k(const unsigned short* __restrict__ qkv,
    unsigned short* __restrict__ y) {
  const int lane = threadIdx.x & 63;
  const int wid = (blockIdx.x * 256 + threadIdx.x) >> 6;   // 16384 waves
  const int qq = lane >> 4, li = lane & 15;
  const int grp = wid & (S_/4 - 1);
  const int bh  = wid >> 9;
  const int hh = bh & (H_ - 1);
  const int b  = bh >> 3;
  const int i  = grp * 4 + qq;
  const float slope = exp2f(-(float)(hh + 1));
  const float inv = 0.088388347648318447f;          // 1/sqrt(128)
  const size_t rowq = ((size_t)(b * S_ + i)) * 3072 + hh * HD_ + li * 8;
  const short8 qv8 = *(const short8*)&qkv[rowq];
  float qf[8];
  #pragma unroll
  for (int e = 0; e < 8; ++e) qf[e] = bf2f((unsigned short)qv8[e]);
  float sc[17];
  #pragma unroll
  for (int jj = 0; jj < 17; ++jj) {
    int j = i - 16 + jj;
    int jc = j < 0 ? 0 : j;
    size_t koff = ((size_t)(b * S_ + jc)) * 3072 + 1024 + hh * HD_ + li * 8;
    short8 kv = *(const short8*)&qkv[koff];
    float p = 0.f;
    #pragma unroll
    for (int e = 0; e < 8; ++e) p += qf[e] * bf2f((unsigned short)kv[e]);
    p += __shfl_xor(p, 8); p += __shfl_xor(p, 4);
    p += __shfl_xor(p, 2); p += __shfl_xor(p, 1);
    sc[jj] = (j >= 0) ? (p * inv + slope * (float)(jj - 16)) : -1e30f;
  }
  float m = sc[0];
  #pragma unroll
  for (int jj = 1; jj < 17; ++jj) m = fmaxf(m, sc[jj]);
  float wsum = 0.f, ax[8];
  #pragma unroll
  for (int e = 0; e < 8; ++e) ax[e] = 0.f;
  #pragma unroll
  for (int jj = 0; jj < 17; ++jj) {
    int j = i - 16 + jj;
    int jc = j < 0 ? 0 : j;
    float wgt = expf(sc[jj] - m);
    size_t voff = ((size_t)(b * S_ + jc)) * 3072 + 2048 + hh * HD_ + li * 8;
    short8 vv = *(const short8*)&qkv[voff];
    wsum += wgt;
    #pragma unroll
    for (int e = 0; e < 8; ++e) ax[e] += wgt * bf2f((unsigned short)vv[e]);
  }
  float rs = 1.f / wsum;
  short8 ov;
  #pragma unroll
  for (int e = 0; e < 8; ++e) ov[e] = (short)f2bf(ax[e] * rs);
  size_t yoff = ((size_t)(b * S_ + i)) * 1024 + hh * HD_ + li * 8;
  *(short8*)&y[yoff] = ov;
}

// ======== 128x128 MFMA GEMM (proven 43%-class): C = A[M,K] @ Bt[N,K]^T ========
// 4 waves 64x64, BK=64, global_load_lds + both-sides XOR swizzle, 32KB LDS.
// NOTE: launch_bounds must stay (256,2) — declaring 3 waves/EU caps VGPR at 84,
// spilling the 128-VGPR accumulator set to scratch (r11: w13 142->299 µs).
__device__ __forceinline__ void stage_tile(const unsigned short* __restrict__ src,
    unsigned short* lds, int rowbase, int K, int k0, int t) {
  #pragma unroll
  for (int it = 0; it < 4; ++it) {
    int g = it * 256 + t;
    int row = g >> 3, slot = g & 7;
    int sc8 = (slot ^ (row & 7)) << 3;
    gload16(&src[(size_t)(rowbase + row) * K + k0 + sc8], &lds[g * 8]);
  }
}

// EPI 0: bf16 store; 1: h += sc[col]*acc; 2: h = x2 + sc[col]*acc
template<int EPI>
__global__ __launch_bounds__(256, 2) void gemm_tn(
    const unsigned short* __restrict__ A, const unsigned short* __restrict__ Bt,
    void* __restrict__ Cout, const float* __restrict__ sc,
    const float* __restrict__ x2, int M, int N, int K) {
  __shared__ __align__(16) unsigned short As[128 * 64];
  __shared__ __align__(16) unsigned short Bs[128 * 64];
  const int t = threadIdx.x;
  const int lane = t & 63, w = t >> 6;
  const int wr = w >> 1, wc = w & 1;
  const int br = blockIdx.y * 128, bc = blockIdx.x * 128;
  const int lr = lane & 15, lk = lane >> 4;
  const int xm = lr & 7;
  f32x4 acc[4][4];
  #pragma unroll
  for (int mi = 0; mi < 4; ++mi)
    #pragma unroll
    for (int ni = 0; ni < 4; ++ni) { f32x4 z = {0.f,0.f,0.f,0.f}; acc[mi][ni] = z; }
  for (int k0 = 0; k0 < K; k0 += 64) {
    stage_tile(A,  As, br, K, k0, t);
    stage_tile(Bt, Bs, bc, K, k0, t);
    __syncthreads();
    #pragma unroll
    for (int kk = 0; kk < 2; ++kk) {
      short8 af[4], bfr[4];
      #pragma unroll
      for (int mi = 0; mi < 4; ++mi)
        af[mi] = *(const short8*)&As[(wr*64 + mi*16 + lr) * 64 + (((kk*4 + lk) ^ xm) << 3)];
      #pragma unroll
      for (int ni = 0; ni < 4; ++ni)
        bfr[ni] = *(const short8*)&Bs[(wc*64 + ni*16 + lr) * 64 + (((kk*4 + lk) ^ xm) << 3)];
      #pragma unroll
      for (int mi = 0; mi < 4; ++mi)
        #pragma unroll
        for (int ni = 0; ni < 4; ++ni)
          acc[mi][ni] = __builtin_amdgcn_mfma_f32_16x16x32_bf16(af[mi], bfr[ni], acc[mi][ni], 0, 0, 0);
    }
    __syncthreads();
  }
  if (EPI == 0) {
    unsigned short* C = (unsigned short*)Cout;
    #pragma unroll
    for (int mi = 0; mi < 4; ++mi)
      #pragma unroll
      for (int ni = 0; ni < 4; ++ni) {
        int row = br + wr * 64 + mi * 16 + lk * 4;
        int col = bc + wc * 64 + ni * 16 + lr;
        #pragma unroll
        for (int r = 0; r < 4; ++r)
          C[(size_t)(row + r) * N + col] = f2bf(acc[mi][ni][r]);
      }
  } else if (EPI == 1) {
    float* hp = (float*)Cout;
    #pragma unroll
    for (int ni = 0; ni < 4; ++ni) {
      int col = bc + wc * 64 + ni * 16 + lr;
      float sv = sc[col];
      #pragma unroll
      for (int mi = 0; mi < 4; ++mi) {
        int row = br + wr * 64 + mi * 16 + lk * 4;
        #pragma unroll
        for (int r = 0; r < 4; ++r)
          hp[(size_t)(row + r) * N + col] += sv * acc[mi][ni][r];
      }
    }
  } else {
    float* hp = (float*)Cout;
    #pragma unroll
    for (int ni = 0; ni < 4; ++ni) {
      int col = bc + wc * 64 + ni * 16 + lr;
      float sv = sc[col];
      #pragma unroll
      for (int mi = 0; mi < 4; ++mi) {
        int row = br + wr * 64 + mi * 16 + lk * 4;
        #pragma unroll
        for (int r = 0; r < 4; ++r)
          hp[(size_t)(row + r) * N + col] = x2[(size_t)(row + r) * N + col] + sv * acc[mi][ni][r];
      }
    }
  }
}

// ---------- fused FFN gate (128² dual-B, proven 142µs): G = bf16(silu(A@W1t^T)*(A@W3t^T)) ----------
__global__ __launch_bounds__(256, 2) void gemm_w13(
    const unsigned short* __restrict__ A, const unsigned short* __restrict__ B1t,
    const unsigned short* __restrict__ B3t, unsigned short* __restrict__ G,
    int M, int N, int K) {
  __shared__ __align__(16) unsigned short As[128 * 64];
  __shared__ __align__(16) unsigned short B1s[128 * 64];
  __shared__ __align__(16) unsigned short B3s[128 * 64];
  const int t = threadIdx.x;
  const int lane = t & 63, w = t >> 6;
  const int wr = w >> 1, wc = w & 1;
  const int br = blockIdx.y * 128, bc = blockIdx.x * 128;
  const int lr = lane & 15, lk = lane >> 4;
  const int xm = lr & 7;
  f32x4 acc1[4][4], acc3[4][4];
  #pragma unroll
  for (int mi = 0; mi < 4; ++mi)
    #pragma unroll
    for (int ni = 0; ni < 4; ++ni) {
      f32x4 z = {0.f,0.f,0.f,0.f}; acc1[mi][ni] = z; acc3[mi][ni] = z;
    }
  for (int k0 = 0; k0 < K; k0 += 64) {
    stage_tile(A,   As,  br, K, k0, t);
    stage_tile(B1t, B1s, bc, K, k0, t);
    stage_tile(B3t, B3s, bc, K, k0, t);
    __syncthreads();
    #pragma unroll
    for (int kk = 0; kk < 2; ++kk) {
      short8 af[4], b1r[4], b3r[4];
      #pragma unroll
      for (int mi = 0; mi < 4; ++mi)
        af[mi] = *(const short8*)&As[(wr*64 + mi*16 + lr) * 64 + (((kk*4 + lk) ^ xm) << 3)];
      #pragma unroll
      for (int ni = 0; ni < 4; ++ni) {
        b1r[ni] = *(const short8*)&B1s[(wc*64 + ni*16 + lr) * 64 + (((kk*4 + lk) ^ xm) << 3)];
        b3r[ni] = *(const short8*)&B3s[(wc*64 + ni*16 + lr) * 64 + (((kk*4 + lk) ^ xm) << 3)];
      }
      #pragma unroll
      for (int mi = 0; mi < 4; ++mi)
        #pragma unroll
        for (int ni = 0; ni < 4; ++ni) {
          acc1[mi][ni] = __builtin_amdgcn_mfma_f32_16x16x32_bf16(af[mi], b1r[ni], acc1[mi][ni], 0, 0, 0);
          acc3[mi][ni] = __builtin_amdgcn_mfma_f32_16x16x32_bf16(af[mi], b3r[ni], acc3[mi][ni], 0, 0, 0);
        }
    }
    __syncthreads();
  }
  #pragma unroll
  for (int mi = 0; mi < 4; ++mi)
    #pragma unroll
    for (int ni = 0; ni < 4; ++ni) {
      int row = br + wr * 64 + mi * 16 + lk * 4;
      int col = bc + wc * 64 + ni * 16 + lr;
      #pragma unroll
      for (int r = 0; r < 4; ++r) {
        float a1 = acc1[mi][ni][r], a3 = acc3[mi][ni][r];
        G[(size_t)(row + r) * N + col] = f2bf(a1 / (1.f + expf(-a1)) * a3);
      }
    }
}

extern "C" void kernel_launch(void* const* d_in, const int* in_sizes, int n_in,
                              void* d_out, int out_size, void* d_ws, size_t ws_size,
                              hipStream_t stream) {
  const float* x    = (const float*)d_in[0];
  const float* wq   = (const float*)d_in[1];
  const float* wk   = (const float*)d_in[2];
  const float* wv   = (const float*)d_in[3];
  const float* wo   = (const float*)d_in[4];
  const float* qnw  = (const float*)d_in[5];
  const float* knw  = (const float*)d_in[6];
  const float* w1   = (const float*)d_in[7];
  const float* w2   = (const float*)d_in[8];
  const float* w3   = (const float*)d_in[9];
  const float* anw  = (const float*)d_in[10];
  const float* fnw  = (const float*)d_in[11];
  const float* asc  = (const float*)d_in[12];
  const float* fsc  = (const float*)d_in[13];

  const size_t MB = 1024 * 1024;
  if (ws_size < 144 * MB) return;

  float* h = (float*)d_out;
  char* ws = (char*)d_ws;
  unsigned short* qkvt = (unsigned short*)ws;             // L x [3072][1024]
  unsigned short* wot  = qkvt + 2u * 3145728u;            // L x [1024][1024]
  unsigned short* w1t  = wot  + 2u * 1048576u;            // L x [4096][1024]
  unsigned short* w3t  = w1t  + 2u * 4194304u;
  unsigned short* w2t  = w3t  + 2u * 4194304u;            // L x [1024][4096]
  unsigned short* xn   = (unsigned short*)(ws + 64 * MB); // 16MB: xnorm / attn-y
  unsigned short* qkv  = (unsigned short*)(ws + 80 * MB); // 48MB [8192][3072]
  unsigned short* gate = qkv;                             // 64MB [8192][4096] (qkv dead)

  f2bf_t_all<<<32768, 256, 0, stream>>>(wq, wk, wv, wo, w1, w3, w2,
                                        qkvt, wot, w1t, w3t, w2t);

  for (int l = 0; l < 2; ++l) {
    // ---- attention ----
    rmsnorm_f2b<<<R_, 256, 0, stream>>>(l == 0 ? x : h, anw + l * D_, xn, 0.01f);
    gemm_tn<0><<<dim3(24, 64), 256, 0, stream>>>(xn, qkvt + (size_t)l*3145728u, qkv,
                                                 nullptr, nullptr, R_, 3072, 1024);
    qknorm_k<<<R_, 256, 0, stream>>>(qkv, qnw + l * 1024, knw + l * 1024);
    attn_k<<<R_ * H_ / 16, 256, 0, stream>>>(qkv, xn);
    if (l == 0)
      gemm_tn<2><<<dim3(8, 64), 256, 0, stream>>>(xn, wot, h, asc, x, R_, 1024, 1024);
    else
      gemm_tn<1><<<dim3(8, 64), 256, 0, stream>>>(xn, wot + 1048576u, h, asc + D_,
                                                  nullptr, R_, 1024, 1024);
    // ---- FFN ----
    rmsnorm_f2b<<<R_, 256, 0, stream>>>(h, fnw + l * D_, xn, 0.01f);
    gemm_w13<<<dim3(32, 64), 256, 0, stream>>>(xn, w1t + (size_t)l*4194304u,
                                               w3t + (size_t)l*4194304u, gate, R_, 4096, 1024);
    gemm_tn<1><<<dim3(8, 64), 256, 0, stream>>>(gate, w2t + (size_t)l*4194304u, h,
                                                fsc + l * D_, nullptr, R_, 1024, 4096);
  }
}

// Round 16
// 820.523 us; speedup vs baseline: 1.1514x; 1.0401x over previous
//
#include <hip/hip_runtime.h>

#define B_ 4
#define S_ 2048
#define D_ 1024
#define H_ 8
#define HD_ 128
#define FF_ 4096
#define R_ (B_*S_)          // 8192 rows

typedef __attribute__((ext_vector_type(8))) short short8;
typedef __attribute__((ext_vector_type(4))) float f32x4;

__device__ __forceinline__ unsigned short f2bf(float f) {
  unsigned int u = __float_as_uint(f);
  return (unsigned short)((u + 0x7fffu + ((u >> 16) & 1u)) >> 16);
}
__device__ __forceinline__ float bf2f(unsigned short s) {
  return __uint_as_float(((unsigned int)s) << 16);
}

typedef const __attribute__((address_space(1))) unsigned int* gas_p;
typedef __attribute__((address_space(3))) unsigned int* las_p;
__device__ __forceinline__ void gload16(const void* g, void* l) {
  __builtin_amdgcn_global_load_lds((gas_p)g, (las_p)l, 16, 0, 0);
}

// ---------- merged transpose+convert of ALL weights (1 dispatch) ----------
__global__ __launch_bounds__(256) void f2bf_t_all(
    const float* __restrict__ wq, const float* __restrict__ wk,
    const float* __restrict__ wv, const float* __restrict__ wo,
    const float* __restrict__ w1, const float* __restrict__ w3,
    const float* __restrict__ w2,
    unsigned short* __restrict__ qkvt, unsigned short* __restrict__ wot,
    unsigned short* __restrict__ w1t, unsigned short* __restrict__ w3t,
    unsigned short* __restrict__ w2t) {
  const int id = blockIdx.x;
  const int l = id >> 14, r = id & 16383;
  const float* src; unsigned short* dst; int Rows, Cols, t2;
  if (r < 4096) {
    Rows = 1024; Cols = 1024; t2 = r & 1023;
    const int wsel = r >> 10;
    if (wsel == 0)      { src = wq + (size_t)l*1048576u; dst = qkvt + (size_t)l*3145728u; }
    else if (wsel == 1) { src = wk + (size_t)l*1048576u; dst = qkvt + (size_t)l*3145728u + 1048576u; }
    else if (wsel == 2) { src = wv + (size_t)l*1048576u; dst = qkvt + (size_t)l*3145728u + 2097152u; }
    else                { src = wo + (size_t)l*1048576u; dst = wot + (size_t)l*1048576u; }
  } else if (r < 12288) {
    Rows = 1024; Cols = 4096; t2 = (r - 4096) & 4095;
    if (r < 8192) { src = w1 + (size_t)l*4194304u; dst = w1t + (size_t)l*4194304u; }
    else          { src = w3 + (size_t)l*4194304u; dst = w3t + (size_t)l*4194304u; }
  } else {
    Rows = 4096; Cols = 1024; t2 = r - 12288;
    src = w2 + (size_t)l*4194304u; dst = w2t + (size_t)l*4194304u;
  }
  const int lgc = (Cols == 4096) ? 7 : 5;
  const int bx = t2 & ((1 << lgc) - 1), by = t2 >> lgc;
  const int r0 = by * 32, c0 = bx * 32;
  __shared__ float tile[32][33];
  const int tx = threadIdx.x & 31, ty = threadIdx.x >> 5;
  #pragma unroll
  for (int j = 0; j < 32; j += 8)
    tile[ty + j][tx] = src[(size_t)(r0 + ty + j) * Cols + c0 + tx];
  __syncthreads();
  #pragma unroll
  for (int j = 0; j < 32; j += 8)
    dst[(size_t)(c0 + ty + j) * Rows + r0 + tx] = f2bf(tile[tx][ty + j]);
}

// ---------- RMSNorm f32 in -> bf16 out ----------
__global__ __launch_bounds__(256) void rmsnorm_f2b(const float* __restrict__ in,
    const float* __restrict__ w, unsigned short* __restrict__ out, float eps) {
  const int row = blockIdx.x, t = threadIdx.x;
  const float4 xv = *(const float4*)&in[(size_t)row * D_ + t * 4];
  float p = xv.x*xv.x + xv.y*xv.y + xv.z*xv.z + xv.w*xv.w;
  #pragma unroll
  for (int off = 32; off >= 1; off >>= 1) p += __shfl_xor(p, off);
  __shared__ float red[4];
  if ((t & 63) == 0) red[t >> 6] = p;
  __syncthreads();
  float scl = rsqrtf((red[0] + red[1] + red[2] + red[3]) * (1.0f / D_) + eps);
  const float4 wv = *(const float4*)&w[t * 4];
  ((ushort4*)out)[(size_t)row * 256 + t] = make_ushort4(
      f2bf(xv.x*scl*wv.x), f2bf(xv.y*scl*wv.y), f2bf(xv.z*scl*wv.z), f2bf(xv.w*scl*wv.w));
}

// ---------- fused q/k RMSNorm over the 1024-wide flat projection, in-place ----------
// NOTE (r13 lesson): do NOT fold this into attn_k — the per-channel weight then
// gets applied 17x per key inside the window loop (+57 µs net).
__global__ __launch_bounds__(256) void qknorm_k(unsigned short* __restrict__ qkv,
    const float* __restrict__ qw, const float* __restrict__ kw) {
  const int row = blockIdx.x, t = threadIdx.x;
  unsigned short* qp = qkv + (size_t)row * 3072;
  unsigned short* kp = qp + 1024;
  const ushort4 qv = ((const ushort4*)qp)[t];
  const ushort4 kv = ((const ushort4*)kp)[t];
  float q0 = bf2f(qv.x), q1 = bf2f(qv.y), q2 = bf2f(qv.z), q3 = bf2f(qv.w);
  float k0 = bf2f(kv.x), k1 = bf2f(kv.y), k2 = bf2f(kv.z), k3 = bf2f(kv.w);
  float pq = q0*q0 + q1*q1 + q2*q2 + q3*q3;
  float pk = k0*k0 + k1*k1 + k2*k2 + k3*k3;
  #pragma unroll
  for (int off = 32; off >= 1; off >>= 1) { pq += __shfl_xor(pq, off); pk += __shfl_xor(pk, off); }
  __shared__ float redq[4], redk[4];
  if ((t & 63) == 0) { redq[t >> 6] = pq; redk[t >> 6] = pk; }
  __syncthreads();
  float sq = rsqrtf((redq[0]+redq[1]+redq[2]+redq[3]) * (1.0f / D_) + 1e-6f);
  float sk = rsqrtf((redk[0]+redk[1]+redk[2]+redk[3]) * (1.0f / D_) + 1e-6f);
  const float4 qwv = *(const float4*)&qw[t * 4];
  const float4 kwv = *(const float4*)&kw[t * 4];
  ((ushort4*)qp)[t] = make_ushort4(f2bf(q0*sq*qwv.x), f2bf(q1*sq*qwv.y),
                                   f2bf(q2*sq*qwv.z), f2bf(q3*sq*qwv.w));
  ((ushort4*)kp)[t] = make_ushort4(f2bf(k0*sk*kwv.x), f2bf(k1*sk*kwv.y),
                                   f2bf(k2*sk*kwv.z), f2bf(k3*sk*kwv.w));
}

// ---------- windowed ALiBi attention: 16 lanes per query (4 queries/wave) ----------
__global__ __launch_bounds__(256) void attn_k(const unsigned short* __restrict__ qkv,
    unsigned short* __restrict__ y) {
  const int lane = threadIdx.x & 63;
  const int wid = (blockIdx.x * 256 + threadIdx.x) >> 6;   // 16384 waves
  const int qq = lane >> 4, li = lane & 15;
  const int grp = wid & (S_/4 - 1);
  const int bh  = wid >> 9;
  const int hh = bh & (H_ - 1);
  const int b  = bh >> 3;
  const int i  = grp * 4 + qq;
  const float slope = exp2f(-(float)(hh + 1));
  const float inv = 0.088388347648318447f;          // 1/sqrt(128)
  const size_t rowq = ((size_t)(b * S_ + i)) * 3072 + hh * HD_ + li * 8;
  const short8 qv8 = *(const short8*)&qkv[rowq];
  float qf[8];
  #pragma unroll
  for (int e = 0; e < 8; ++e) qf[e] = bf2f((unsigned short)qv8[e]);
  float sc[17];
  #pragma unroll
  for (int jj = 0; jj < 17; ++jj) {
    int j = i - 16 + jj;
    int jc = j < 0 ? 0 : j;
    size_t koff = ((size_t)(b * S_ + jc)) * 3072 + 1024 + hh * HD_ + li * 8;
    short8 kv = *(const short8*)&qkv[koff];
    float p = 0.f;
    #pragma unroll
    for (int e = 0; e < 8; ++e) p += qf[e] * bf2f((unsigned short)kv[e]);
    p += __shfl_xor(p, 8); p += __shfl_xor(p, 4);
    p += __shfl_xor(p, 2); p += __shfl_xor(p, 1);
    sc[jj] = (j >= 0) ? (p * inv + slope * (float)(jj - 16)) : -1e30f;
  }
  float m = sc[0];
  #pragma unroll
  for (int jj = 1; jj < 17; ++jj) m = fmaxf(m, sc[jj]);
  float wsum = 0.f, ax[8];
  #pragma unroll
  for (int e = 0; e < 8; ++e) ax[e] = 0.f;
  #pragma unroll
  for (int jj = 0; jj < 17; ++jj) {
    int j = i - 16 + jj;
    int jc = j < 0 ? 0 : j;
    float wgt = expf(sc[jj] - m);
    size_t voff = ((size_t)(b * S_ + jc)) * 3072 + 2048 + hh * HD_ + li * 8;
    short8 vv = *(const short8*)&qkv[voff];
    wsum += wgt;
    #pragma unroll
    for (int e = 0; e < 8; ++e) ax[e] += wgt * bf2f((unsigned short)vv[e]);
  }
  float rs = 1.f / wsum;
  short8 ov;
  #pragma unroll
  for (int e = 0; e < 8; ++e) ov[e] = (short)f2bf(ax[e] * rs);
  size_t yoff = ((size_t)(b * S_ + i)) * 1024 + hh * HD_ + li * 8;
  *(short8*)&y[yoff] = ov;
}

// ======== 128x128 MFMA GEMM (proven 43%-class) — qkv / w13 ========
// NOTE: launch_bounds must stay (256,2) — declaring 3 waves/EU caps VGPR at 84,
// spilling the 128-VGPR accumulator set to scratch (r11: w13 142->299 µs).
__device__ __forceinline__ void stage_tile(const unsigned short* __restrict__ src,
    unsigned short* lds, int rowbase, int K, int k0, int t) {
  #pragma unroll
  for (int it = 0; it < 4; ++it) {
    int g = it * 256 + t;
    int row = g >> 3, slot = g & 7;
    int sc8 = (slot ^ (row & 7)) << 3;
    gload16(&src[(size_t)(rowbase + row) * K + k0 + sc8], &lds[g * 8]);
  }
}

// EPI 0: bf16 store; 1: h += sc[col]*acc; 2: h = x2 + sc[col]*acc
template<int EPI>
__global__ __launch_bounds__(256, 2) void gemm_tn(
    const unsigned short* __restrict__ A, const unsigned short* __restrict__ Bt,
    void* __restrict__ Cout, const float* __restrict__ sc,
    const float* __restrict__ x2, int M, int N, int K) {
  __shared__ __align__(16) unsigned short As[128 * 64];
  __shared__ __align__(16) unsigned short Bs[128 * 64];
  const int t = threadIdx.x;
  const int lane = t & 63, w = t >> 6;
  const int wr = w >> 1, wc = w & 1;
  const int br = blockIdx.y * 128, bc = blockIdx.x * 128;
  const int lr = lane & 15, lk = lane >> 4;
  const int xm = lr & 7;
  f32x4 acc[4][4];
  #pragma unroll
  for (int mi = 0; mi < 4; ++mi)
    #pragma unroll
    for (int ni = 0; ni < 4; ++ni) { f32x4 z = {0.f,0.f,0.f,0.f}; acc[mi][ni] = z; }
  for (int k0 = 0; k0 < K; k0 += 64) {
    stage_tile(A,  As, br, K, k0, t);
    stage_tile(Bt, Bs, bc, K, k0, t);
    __syncthreads();
    #pragma unroll
    for (int kk = 0; kk < 2; ++kk) {
      short8 af[4], bfr[4];
      #pragma unroll
      for (int mi = 0; mi < 4; ++mi)
        af[mi] = *(const short8*)&As[(wr*64 + mi*16 + lr) * 64 + (((kk*4 + lk) ^ xm) << 3)];
      #pragma unroll
      for (int ni = 0; ni < 4; ++ni)
        bfr[ni] = *(const short8*)&Bs[(wc*64 + ni*16 + lr) * 64 + (((kk*4 + lk) ^ xm) << 3)];
      #pragma unroll
      for (int mi = 0; mi < 4; ++mi)
        #pragma unroll
        for (int ni = 0; ni < 4; ++ni)
          acc[mi][ni] = __builtin_amdgcn_mfma_f32_16x16x32_bf16(af[mi], bfr[ni], acc[mi][ni], 0, 0, 0);
    }
    __syncthreads();
  }
  if (EPI == 0) {
    unsigned short* C = (unsigned short*)Cout;
    #pragma unroll
    for (int mi = 0; mi < 4; ++mi)
      #pragma unroll
      for (int ni = 0; ni < 4; ++ni) {
        int row = br + wr * 64 + mi * 16 + lk * 4;
        int col = bc + wc * 64 + ni * 16 + lr;
        #pragma unroll
        for (int r = 0; r < 4; ++r)
          C[(size_t)(row + r) * N + col] = f2bf(acc[mi][ni][r]);
      }
  } else if (EPI == 1) {
    float* hp = (float*)Cout;
    #pragma unroll
    for (int ni = 0; ni < 4; ++ni) {
      int col = bc + wc * 64 + ni * 16 + lr;
      float sv = sc[col];
      #pragma unroll
      for (int mi = 0; mi < 4; ++mi) {
        int row = br + wr * 64 + mi * 16 + lk * 4;
        #pragma unroll
        for (int r = 0; r < 4; ++r)
          hp[(size_t)(row + r) * N + col] += sv * acc[mi][ni][r];
      }
    }
  } else {
    float* hp = (float*)Cout;
    #pragma unroll
    for (int ni = 0; ni < 4; ++ni) {
      int col = bc + wc * 64 + ni * 16 + lr;
      float sv = sc[col];
      #pragma unroll
      for (int mi = 0; mi < 4; ++mi) {
        int row = br + wr * 64 + mi * 16 + lk * 4;
        #pragma unroll
        for (int r = 0; r < 4; ++r)
          hp[(size_t)(row + r) * N + col] = x2[(size_t)(row + r) * N + col] + sv * acc[mi][ni][r];
      }
    }
  }
}

// ======== 3-buffer deep-prefetch GEMM (wo / w2): 256x128, 512 thr, 8 waves ========
// Prefetch distance 2; per K-tile: 12 ds_read || stage t+2 (6 gload16/thread),
// vmcnt(6) [tile t+1 stays in flight], lgkmcnt(0), ONE raw s_barrier, 32 MFMA.
// Restage of a buffer happens 1 full iteration after its last read; all reads
// complete before each wave's pre-barrier lgkmcnt(0) -> chip-wide safe (r8 lesson).
// EPI 1: h += sc[col]*acc; EPI 2: h = x2 + sc[col]*acc
template<int EPI>
__global__ __launch_bounds__(512, 1) void gemm_dp(
    const unsigned short* __restrict__ A, const unsigned short* __restrict__ Bt,
    float* __restrict__ hp, const float* __restrict__ sc,
    const float* __restrict__ x2, int M, int N, int K) {
  __shared__ __align__(16) unsigned short lds[3][24576];  // 3 x (A 256x64 + B 128x64) = 144KB
  const int t = threadIdx.x;
  const int lane = t & 63, w = t >> 6;
  const int wm = w >> 2, wn = w & 3;
  const int lr = lane & 15, lk = lane >> 4;
  const int xm = lr & 7;
  const int br = blockIdx.y << 8, bc = blockIdx.x << 7;

  const unsigned short* Ab = A + (size_t)br * K;
  const unsigned short* Bb = Bt + (size_t)bc * K;

  auto stage = [&](int buf, int k0) {
    unsigned short* d = lds[buf];
    #pragma unroll
    for (int j = 0; j < 4; ++j) {           // A: 256 rows x 8 slots
      int idx = t + (j << 9);
      int row = idx >> 3, slot = idx & 7;
      gload16(Ab + (size_t)row * K + k0 + ((slot ^ (row & 7)) << 3),
              &d[row * 64 + slot * 8]);
    }
    #pragma unroll
    for (int j = 0; j < 2; ++j) {           // B: 128 rows x 8 slots
      int idx = t + (j << 9);
      int row = idx >> 3, slot = idx & 7;
      gload16(Bb + (size_t)row * K + k0 + ((slot ^ (row & 7)) << 3),
              &d[16384 + row * 64 + slot * 8]);
    }
  };

  f32x4 acc[8][2];
  #pragma unroll
  for (int mi = 0; mi < 8; ++mi)
    #pragma unroll
    for (int ni = 0; ni < 2; ++ni) { f32x4 z = {0.f,0.f,0.f,0.f}; acc[mi][ni] = z; }

  const int NT = K >> 6;
  stage(0, 0); stage(1, 64);
  asm volatile("s_waitcnt vmcnt(6)" ::: "memory");   // tile 0 landed
  __builtin_amdgcn_s_barrier();

  #pragma unroll 1
  for (int kt = 0; kt < NT; ++kt) {
    const unsigned short* cur = lds[kt % 3];
    short8 af[2][8], bfr[2][2];
    #pragma unroll
    for (int ks = 0; ks < 2; ++ks) {
      #pragma unroll
      for (int mf = 0; mf < 8; ++mf)
        af[ks][mf] = *(const short8*)&cur[(wm*128 + mf*16 + lr)*64 + (((ks*4+lk)^xm)<<3)];
      #pragma unroll
      for (int nf = 0; nf < 2; ++nf)
        bfr[ks][nf] = *(const short8*)&cur[16384 + (wn*32 + nf*16 + lr)*64 + (((ks*4+lk)^xm)<<3)];
    }
    const int kp = (kt + 2 < NT) ? ((kt + 2) << 6) : 0;   // dummy restage on tail
    stage((kt + 2) % 3, kp);
    asm volatile("s_waitcnt vmcnt(6)" ::: "memory");      // tile kt+1 landed
    asm volatile("s_waitcnt lgkmcnt(0)" ::: "memory");    // my frags in regs
    __builtin_amdgcn_sched_barrier(0);
    __builtin_amdgcn_s_barrier();
    __builtin_amdgcn_s_setprio(1);
    #pragma unroll
    for (int mf = 0; mf < 8; ++mf)
      #pragma unroll
      for (int nf = 0; nf < 2; ++nf)
        #pragma unroll
        for (int ks = 0; ks < 2; ++ks)
          acc[mf][nf] = __builtin_amdgcn_mfma_f32_16x16x32_bf16(af[ks][mf], bfr[ks][nf], acc[mf][nf], 0, 0, 0);
    __builtin_amdgcn_s_setprio(0);
  }

  #pragma unroll
  for (int nf = 0; nf < 2; ++nf) {
    int col = bc + wn*32 + nf*16 + lr;
    float sv = sc[col];
    #pragma unroll
    for (int mf = 0; mf < 8; ++mf) {
      int row = br + wm*128 + mf*16 + lk*4;
      #pragma unroll
      for (int r = 0; r < 4; ++r) {
        if (EPI == 1)
          hp[(size_t)(row + r) * N + col] += sv * acc[mf][nf][r];
        else
          hp[(size_t)(row + r) * N + col] = x2[(size_t)(row + r) * N + col] + sv * acc[mf][nf][r];
      }
    }
  }
}

// ---------- fused FFN gate (128² dual-B, proven 142µs) ----------
__global__ __launch_bounds__(256, 2) void gemm_w13(
    const unsigned short* __restrict__ A, const unsigned short* __restrict__ B1t,
    const unsigned short* __restrict__ B3t, unsigned short* __restrict__ G,
    int M, int N, int K) {
  __shared__ __align__(16) unsigned short As[128 * 64];
  __shared__ __align__(16) unsigned short B1s[128 * 64];
  __shared__ __align__(16) unsigned short B3s[128 * 64];
  const int t = threadIdx.x;
  const int lane = t & 63, w = t >> 6;
  const int wr = w >> 1, wc = w & 1;
  const int br = blockIdx.y * 128, bc = blockIdx.x * 128;
  const int lr = lane & 15, lk = lane >> 4;
  const int xm = lr & 7;
  f32x4 acc1[4][4], acc3[4][4];
  #pragma unroll
  for (int mi = 0; mi < 4; ++mi)
    #pragma unroll
    for (int ni = 0; ni < 4; ++ni) {
      f32x4 z = {0.f,0.f,0.f,0.f}; acc1[mi][ni] = z; acc3[mi][ni] = z;
    }
  for (int k0 = 0; k0 < K; k0 += 64) {
    stage_tile(A,   As,  br, K, k0, t);
    stage_tile(B1t, B1s, bc, K, k0, t);
    stage_tile(B3t, B3s, bc, K, k0, t);
    __syncthreads();
    #pragma unroll
    for (int kk = 0; kk < 2; ++kk) {
      short8 af[4], b1r[4], b3r[4];
      #pragma unroll
      for (int mi = 0; mi < 4; ++mi)
        af[mi] = *(const short8*)&As[(wr*64 + mi*16 + lr) * 64 + (((kk*4 + lk) ^ xm) << 3)];
      #pragma unroll
      for (int ni = 0; ni < 4; ++ni) {
        b1r[ni] = *(const short8*)&B1s[(wc*64 + ni*16 + lr) * 64 + (((kk*4 + lk) ^ xm) << 3)];
        b3r[ni] = *(const short8*)&B3s[(wc*64 + ni*16 + lr) * 64 + (((kk*4 + lk) ^ xm) << 3)];
      }
      #pragma unroll
      for (int mi = 0; mi < 4; ++mi)
        #pragma unroll
        for (int ni = 0; ni < 4; ++ni) {
          acc1[mi][ni] = __builtin_amdgcn_mfma_f32_16x16x32_bf16(af[mi], b1r[ni], acc1[mi][ni], 0, 0, 0);
          acc3[mi][ni] = __builtin_amdgcn_mfma_f32_16x16x32_bf16(af[mi], b3r[ni], acc3[mi][ni], 0, 0, 0);
        }
    }
    __syncthreads();
  }
  #pragma unroll
  for (int mi = 0; mi < 4; ++mi)
    #pragma unroll
    for (int ni = 0; ni < 4; ++ni) {
      int row = br + wr * 64 + mi * 16 + lk * 4;
      int col = bc + wc * 64 + ni * 16 + lr;
      #pragma unroll
      for (int r = 0; r < 4; ++r) {
        float a1 = acc1[mi][ni][r], a3 = acc3[mi][ni][r];
        G[(size_t)(row + r) * N + col] = f2bf(a1 / (1.f + expf(-a1)) * a3);
      }
    }
}

extern "C" void kernel_launch(void* const* d_in, const int* in_sizes, int n_in,
                              void* d_out, int out_size, void* d_ws, size_t ws_size,
                              hipStream_t stream) {
  const float* x    = (const float*)d_in[0];
  const float* wq   = (const float*)d_in[1];
  const float* wk   = (const float*)d_in[2];
  const float* wv   = (const float*)d_in[3];
  const float* wo   = (const float*)d_in[4];
  const float* qnw  = (const float*)d_in[5];
  const float* knw  = (const float*)d_in[6];
  const float* w1   = (const float*)d_in[7];
  const float* w2   = (const float*)d_in[8];
  const float* w3   = (const float*)d_in[9];
  const float* anw  = (const float*)d_in[10];
  const float* fnw  = (const float*)d_in[11];
  const float* asc  = (const float*)d_in[12];
  const float* fsc  = (const float*)d_in[13];

  const size_t MB = 1024 * 1024;
  if (ws_size < 144 * MB) return;

  float* h = (float*)d_out;
  char* ws = (char*)d_ws;
  unsigned short* qkvt = (unsigned short*)ws;             // L x [3072][1024]
  unsigned short* wot  = qkvt + 2u * 3145728u;            // L x [1024][1024]
  unsigned short* w1t  = wot  + 2u * 1048576u;            // L x [4096][1024]
  unsigned short* w3t  = w1t  + 2u * 4194304u;
  unsigned short* w2t  = w3t  + 2u * 4194304u;            // L x [1024][4096]
  unsigned short* xn   = (unsigned short*)(ws + 64 * MB); // 16MB: xnorm / attn-y
  unsigned short* qkv  = (unsigned short*)(ws + 80 * MB); // 48MB [8192][3072]
  unsigned short* gate = qkv;                             // 64MB [8192][4096] (qkv dead)

  f2bf_t_all<<<32768, 256, 0, stream>>>(wq, wk, wv, wo, w1, w3, w2,
                                        qkvt, wot, w1t, w3t, w2t);

  for (int l = 0; l < 2; ++l) {
    // ---- attention ----
    rmsnorm_f2b<<<R_, 256, 0, stream>>>(l == 0 ? x : h, anw + l * D_, xn, 0.01f);
    gemm_tn<0><<<dim3(24, 64), 256, 0, stream>>>(xn, qkvt + (size_t)l*3145728u, qkv,
                                                 nullptr, nullptr, R_, 3072, 1024);
    qknorm_k<<<R_, 256, 0, stream>>>(qkv, qnw + l * 1024, knw + l * 1024);
    attn_k<<<R_ * H_ / 16, 256, 0, stream>>>(qkv, xn);
    if (l == 0)
      gemm_dp<2><<<dim3(8, 32), 512, 0, stream>>>(xn, wot, h, asc, x, R_, 1024, 1024);
    else
      gemm_dp<1><<<dim3(8, 32), 512, 0, stream>>>(xn, wot + 1048576u, h, asc + D_,
                                                  nullptr, R_, 1024, 1024);
    // ---- FFN ----
    rmsnorm_f2b<<<R_, 256, 0, stream>>>(h, fnw + l * D_, xn, 0.01f);
    gemm_w13<<<dim3(32, 64), 256, 0, stream>>>(xn, w1t + (size_t)l*4194304u,
                                               w3t + (size_t)l*4194304u, gate, R_, 4096, 1024);
    gemm_dp<1><<<dim3(8, 32), 512, 0, stream>>>(gate, w2t + (size_t)l*4194304u, h,
                                                fsc + l * D_, nullptr, R_, 1024, 4096);
  }
}